// Round 6
// baseline (570.389 us; speedup 1.0000x reference)
//
#include <hip/hip_runtime.h>
#include <hip/hip_bf16.h>
#include <stdint.h>

#define FDIM   1024
#define NCLS   100
#define CDIM   512
#define NBATCH 4096

typedef __attribute__((ext_vector_type(8))) short short8;
typedef __attribute__((ext_vector_type(4))) float f32x4;

typedef const __attribute__((address_space(1))) unsigned int guint;
typedef __attribute__((address_space(3))) unsigned int luint;

__device__ __forceinline__ void gl_lds16(const unsigned short* g, unsigned short* l) {
    __builtin_amdgcn_global_load_lds((guint*)g, (luint*)l, 16, 0, 0);
}

__device__ __forceinline__ unsigned short f2bf_bits(float f) {
    union { float f; uint32_t u; } v; v.f = f;
    uint32_t u = v.u;
    return (unsigned short)((u + 0x7FFFu + ((u >> 16) & 1u)) >> 16);
}

// ---- convert x: f32 [4096][1024] -> bf16 same layout ----
__global__ void cvt_x_kernel(const float* __restrict__ x, unsigned short* __restrict__ xb) {
    const int i = (blockIdx.x * 256 + threadIdx.x) * 8;
    f32x4 a = *(const f32x4*)(x + i);
    f32x4 b = *(const f32x4*)(x + i + 4);
    short8 h;
#pragma unroll
    for (int e = 0; e < 4; ++e) { h[e] = (short)f2bf_bits(a[e]); h[e + 4] = (short)f2bf_bits(b[e]); }
    *(short8*)(xb + i) = h;
}

// ---- convert weight: f32 [m][n][j] -> bf16 [n][m][j] ----
__global__ void cvt_w_kernel(const float* __restrict__ w, unsigned short* __restrict__ wb) {
    const int mn = blockIdx.x;              // m*NCLS + n
    const int m = mn / NCLS, n = mn % NCLS;
    const float* src = w + (size_t)mn * FDIM;
    unsigned short* dst = wb + ((size_t)n * CDIM + m) * FDIM;
    const int c = threadIdx.x * 8;
    f32x4 a = *(const f32x4*)(src + c);
    f32x4 b = *(const f32x4*)(src + c + 4);
    short8 h;
#pragma unroll
    for (int e = 0; e < 4; ++e) { h[e] = (short)f2bf_bits(a[e]); h[e + 4] = (short)f2bf_bits(b[e]); }
    *(short8*)(dst + c) = h;
}

// ---- fused DUQ, 256x256x64, windowed frag-pipeline (counted lgkmcnt) ----
// Per K-tile: ONE barrier. Windows:
//  entry: issue A0(8),B0(4),B1(4) reads; stage c0,c1,c2;  lgkm(4); sb0
//  W0: MFMA Q(0,0) | issue A1(8) | stage c3,c4,c5;        lgkm(8); sb0
//  W1: MFMA Q(0,1) | stage c6,c7;                          lgkm(0); sb0
//  W2: MFMA Q(1,1)
//  W3: MFMA Q(1,0)  [+ panel epilogue, ends with lgkm(0)]
//  vmcnt(0)  (tile t+1 chunks issued >=1 window back -> instant)
//  s_barrier
// Counted lgkm relies on: in-order DS retirement; gl_lds counts vmcnt only;
// no other lgkm ops inside counted windows (epilogue drains itself).
__global__ __launch_bounds__(512, 2)
void duq8(const unsigned short* __restrict__ xb, const unsigned short* __restrict__ wb,
          const float* __restrict__ csum, const float* __restrict__ cnum,
          float* __restrict__ out) {
    __shared__ unsigned short lsA[2][256 * 64];   // 2 x 32 KB
    __shared__ unsigned short lsB[2][256 * 64];   // 2 x 32 KB
    __shared__ float c_lds[CDIM];
    __shared__ float red[4][256];

    const int t    = threadIdx.x;
    const int bid  = blockIdx.x;
    const int n    = bid >> 4;       // class 0..99
    const int rt   = bid & 15;       // 256-row batch tile
    const int lane = t & 63;
    const int wm   = (t >> 6) >> 2;  // 0..1 : rows wm*128..+127
    const int wn   = (t >> 6) & 3;   // 0..3 : cols wn*64..+63
    const int ln15 = lane & 15;
    const int hi   = lane >> 4;

    {
        const float inv = 1.0f / cnum[n];
        for (int m = t; m < CDIM; m += 512)
            c_lds[m] = csum[(size_t)m * NCLS + n] * inv;
    }
    __syncthreads();   // full drain fine here (nothing pipelined yet)

    // staging: thread covers row chunkbase+(t>>3), 16B at pre-swizzled col
    const int st_r = t >> 3;                       // 0..63
    const int st_c = ((t & 7) ^ (st_r & 7)) * 8;
    const unsigned short* gA = xb + ((size_t)(rt * 256 + st_r)) * FDIM + st_c;
    const unsigned short* gBb = wb + ((size_t)n * CDIM + st_r) * FDIM + st_c;
    const int ldst = st_r * 64 + (t & 7) * 8;      // linear dest (elements)

    auto stageA = [&](int rowoff, int tt, int bsel) {
        const int k_ = (tt & 15) * 64;
        gl_lds16(gA + (size_t)rowoff * FDIM + k_, &lsA[bsel][rowoff * 64 + ldst]);
    };
    auto stageB = [&](int rowoff, int tt, int bsel) {
        const int k_ = (tt & 15) * 64;
        const int pn_ = tt >> 4;
        gl_lds16(gBb + (size_t)(pn_ * 256 + rowoff) * FDIM + k_, &lsB[bsel][rowoff * 64 + ldst]);
    };

    f32x4 acc[8][4];
#pragma unroll
    for (int i = 0; i < 8; ++i)
#pragma unroll
        for (int j = 0; j < 4; ++j) acc[i][j] = f32x4{0.0f, 0.0f, 0.0f, 0.0f};

    // prologue: stage tile 0 fully, drain, barrier
    stageA(0, 0, 0); stageA(128, 0, 0);
    stageB(0, 0, 0); stageB(64, 0, 0); stageB(128, 0, 0); stageB(192, 0, 0);
    stageA(64, 0, 0); stageA(192, 0, 0);
    asm volatile("s_waitcnt vmcnt(0)" ::: "memory");
    __builtin_amdgcn_s_barrier();

    short8 a0[4][2], a1[4][2], b0[2][2], b1[2][2];

    for (int it = 0; it < 32; ++it) {
        const int bs = it & 1;
        const bool more = (it + 1 < 32);
        const char* lA = (const char*)lsA[bs];
        const char* lB = (const char*)lsB[bs];

        // ---- entry: issue A0(8), B0(4), B1(4); stage c0..c2 ----
#pragma unroll
        for (int i = 0; i < 4; ++i) {
            const int row = wm * 128 + i * 16 + ln15;
#pragma unroll
            for (int kk = 0; kk < 2; ++kk) {
                const int ba = (row * 128 + (kk * 32 + hi * 8) * 2) ^ ((row & 7) << 4);
                a0[i][kk] = *(const short8*)(lA + ba);
            }
        }
#pragma unroll
        for (int j = 0; j < 2; ++j) {
            const int row = wn * 64 + j * 16 + ln15;
#pragma unroll
            for (int kk = 0; kk < 2; ++kk) {
                const int bb = (row * 128 + (kk * 32 + hi * 8) * 2) ^ ((row & 7) << 4);
                b0[j][kk] = *(const short8*)(lB + bb);
            }
        }
#pragma unroll
        for (int j = 0; j < 2; ++j) {
            const int row = wn * 64 + (2 + j) * 16 + ln15;
#pragma unroll
            for (int kk = 0; kk < 2; ++kk) {
                const int bb = (row * 128 + (kk * 32 + hi * 8) * 2) ^ ((row & 7) << 4);
                b1[j][kk] = *(const short8*)(lB + bb);
            }
        }
        if (more) { stageA(0, it + 1, bs ^ 1); stageA(128, it + 1, bs ^ 1); stageB(0, it + 1, bs ^ 1); }
        asm volatile("s_waitcnt lgkmcnt(4)" ::: "memory");   // A0,B0 ready (B1 maybe pending)
        __builtin_amdgcn_sched_barrier(0);

        // ---- W0: MFMA Q(0,0) | issue A1(8) | stage c3..c5 ----
        __builtin_amdgcn_s_setprio(1);
#pragma unroll
        for (int i = 0; i < 4; ++i)
#pragma unroll
            for (int j = 0; j < 2; ++j)
#pragma unroll
                for (int kk = 0; kk < 2; ++kk)
                    acc[i][j] = __builtin_amdgcn_mfma_f32_16x16x32_bf16(
                        a0[i][kk], b0[j][kk], acc[i][j], 0, 0, 0);
        __builtin_amdgcn_s_setprio(0);
#pragma unroll
        for (int i = 0; i < 4; ++i) {
            const int row = wm * 128 + 64 + i * 16 + ln15;
#pragma unroll
            for (int kk = 0; kk < 2; ++kk) {
                const int ba = (row * 128 + (kk * 32 + hi * 8) * 2) ^ ((row & 7) << 4);
                a1[i][kk] = *(const short8*)(lA + ba);
            }
        }
        if (more) { stageB(64, it + 1, bs ^ 1); stageB(128, it + 1, bs ^ 1); stageB(192, it + 1, bs ^ 1); }
        asm volatile("s_waitcnt lgkmcnt(8)" ::: "memory");   // B1 ready (A1 maybe pending)
        __builtin_amdgcn_sched_barrier(0);

        // ---- W1: MFMA Q(0,1) | stage c6,c7 ----
        __builtin_amdgcn_s_setprio(1);
#pragma unroll
        for (int i = 0; i < 4; ++i)
#pragma unroll
            for (int j = 0; j < 2; ++j)
#pragma unroll
                for (int kk = 0; kk < 2; ++kk)
                    acc[i][2 + j] = __builtin_amdgcn_mfma_f32_16x16x32_bf16(
                        a0[i][kk], b1[j][kk], acc[i][2 + j], 0, 0, 0);
        __builtin_amdgcn_s_setprio(0);
        if (more) { stageA(64, it + 1, bs ^ 1); stageA(192, it + 1, bs ^ 1); }
        asm volatile("s_waitcnt lgkmcnt(0)" ::: "memory");   // A1 ready
        __builtin_amdgcn_sched_barrier(0);

        // ---- W2: MFMA Q(1,1) ----
        __builtin_amdgcn_s_setprio(1);
#pragma unroll
        for (int i = 0; i < 4; ++i)
#pragma unroll
            for (int j = 0; j < 2; ++j)
#pragma unroll
                for (int kk = 0; kk < 2; ++kk)
                    acc[4 + i][2 + j] = __builtin_amdgcn_mfma_f32_16x16x32_bf16(
                        a1[i][kk], b1[j][kk], acc[4 + i][2 + j], 0, 0, 0);
        // ---- W3: MFMA Q(1,0) ----
#pragma unroll
        for (int i = 0; i < 4; ++i)
#pragma unroll
            for (int j = 0; j < 2; ++j)
#pragma unroll
                for (int kk = 0; kk < 2; ++kk)
                    acc[4 + i][j] = __builtin_amdgcn_mfma_f32_16x16x32_bf16(
                        a1[i][kk], b0[j][kk], acc[4 + i][j], 0, 0, 0);
        __builtin_amdgcn_s_setprio(0);

        if ((it & 15) == 15) {       // panel epilogue: fold (z-c)^2
            const int pn = it >> 4;
            float p[8][4];
#pragma unroll
            for (int i = 0; i < 8; ++i)
#pragma unroll
                for (int r = 0; r < 4; ++r) p[i][r] = 0.0f;
#pragma unroll
            for (int i = 0; i < 8; ++i)
#pragma unroll
                for (int j = 0; j < 4; ++j) {
                    const int m = pn * 256 + wn * 64 + j * 16 + ln15;
                    const float c = c_lds[m];
#pragma unroll
                    for (int r = 0; r < 4; ++r) {
                        const float d = acc[i][j][r] - c;
                        p[i][r] += d * d;
                        acc[i][j][r] = 0.0f;
                    }
                }
#pragma unroll
            for (int i = 0; i < 8; ++i)
#pragma unroll
                for (int r = 0; r < 4; ++r) {
                    float v = p[i][r];
                    v += __shfl_xor(v, 1);
                    v += __shfl_xor(v, 2);
                    v += __shfl_xor(v, 4);
                    v += __shfl_xor(v, 8);
                    p[i][r] = v;
                }
            if (ln15 == 0) {
#pragma unroll
                for (int i = 0; i < 8; ++i)
#pragma unroll
                    for (int r = 0; r < 4; ++r) {
                        const int row = wm * 128 + i * 16 + hi * 4 + r;
                        if (pn == 0) red[wn][row] = p[i][r];
                        else         red[wn][row] += p[i][r];
                    }
            }
            asm volatile("s_waitcnt lgkmcnt(0)" ::: "memory");  // drain epilogue ds ops
        }

        asm volatile("s_waitcnt vmcnt(0)" ::: "memory");  // t+1 staged (issued >=1 window ago)
        __builtin_amdgcn_s_barrier();
    }

    __syncthreads();
    if (t < 256) {
        const float sq = (red[0][t] + red[1][t] + red[2][t] + red[3][t]) * (1.0f / 512.0f);
        const float lc = -50.0f * sq;                    // -sq / (2*0.1^2)
        const size_t b = (size_t)rt * 256 + t;
        out[b * NCLS + n] = expf(lc);
        out[(size_t)NBATCH * NCLS + b * NCLS + n] = lc;
    }
}

// ---- fallback (no workspace): reg-staged inline-convert variant (r1, verified) ----
__global__ __launch_bounds__(256, 2)
void duq_fallback(const float* __restrict__ x, const float* __restrict__ w,
                  const float* __restrict__ csum, const float* __restrict__ cnum,
                  float* __restrict__ out) {
    __shared__ unsigned short lsA[128 * 64];
    __shared__ unsigned short lsB[128 * 64];
    __shared__ float c_lds[CDIM];
    __shared__ float red[2][128];

    const int t = threadIdx.x;
    const int n    = blockIdx.x >> 5;
    const int tile = blockIdx.x & 31;
    const int lane = t & 63;
    const int wid  = t >> 6;
    const int wrow = wid >> 1;
    const int wcol = wid & 1;
    const int ln15 = lane & 15;
    const int hi   = lane >> 4;

    {
        const float inv = 1.0f / cnum[n];
        for (int m = t; m < CDIM; m += 256)
            c_lds[m] = csum[(size_t)m * NCLS + n] * inv;
    }

    const int srow = t >> 3;
    const int scol = (t & 7) * 8;
    const int swz  = (srow & 7) << 4;

    float p[16];
#pragma unroll
    for (int q = 0; q < 16; ++q) p[q] = 0.0f;

    for (int chunk = 0; chunk < 4; ++chunk) {
        f32x4 acc[4][4];
#pragma unroll
        for (int i = 0; i < 4; ++i)
#pragma unroll
            for (int j = 0; j < 4; ++j)
                acc[i][j] = f32x4{0.0f, 0.0f, 0.0f, 0.0f};

        for (int ks = 0; ks < 16; ++ks) {
            const int k = ks * 64;
            __syncthreads();
#pragma unroll
            for (int pp = 0; pp < 4; ++pp) {
                const int row = pp * 32 + srow;
                const float* pa = x + ((size_t)(tile * 128 + row)) * FDIM + k + scol;
                const float* pb = w + ((size_t)(chunk * 128 + row) * NCLS + n) * FDIM + k + scol;
                f32x4 a0 = *(const f32x4*)pa, a1 = *(const f32x4*)(pa + 4);
                f32x4 b0 = *(const f32x4*)pb, b1 = *(const f32x4*)(pb + 4);
                short8 ha, hb;
#pragma unroll
                for (int e = 0; e < 4; ++e) {
                    ha[e] = (short)f2bf_bits(a0[e]); ha[e + 4] = (short)f2bf_bits(a1[e]);
                    hb[e] = (short)f2bf_bits(b0[e]); hb[e + 4] = (short)f2bf_bits(b1[e]);
                }
                const int byte = (row * 128 + scol * 2) ^ swz;
                *(short8*)((char*)lsA + byte) = ha;
                *(short8*)((char*)lsB + byte) = hb;
            }
            __syncthreads();
#pragma unroll
            for (int kk = 0; kk < 2; ++kk) {
                short8 afr[4], bfr[4];
#pragma unroll
                for (int i = 0; i < 4; ++i) {
                    const int rowA = wrow * 64 + i * 16 + ln15;
                    const int ba = (rowA * 128 + (kk * 32 + hi * 8) * 2) ^ ((rowA & 7) << 4);
                    afr[i] = *(const short8*)((const char*)lsA + ba);
                    const int rowB = wcol * 64 + i * 16 + ln15;
                    const int bb = (rowB * 128 + (kk * 32 + hi * 8) * 2) ^ ((rowB & 7) << 4);
                    bfr[i] = *(const short8*)((const char*)lsB + bb);
                }
#pragma unroll
                for (int i = 0; i < 4; ++i)
#pragma unroll
                    for (int j = 0; j < 4; ++j)
                        acc[i][j] = __builtin_amdgcn_mfma_f32_16x16x32_bf16(afr[i], bfr[j], acc[i][j], 0, 0, 0);
            }
        }

#pragma unroll
        for (int i = 0; i < 4; ++i)
#pragma unroll
            for (int j = 0; j < 4; ++j) {
                const int m = chunk * 128 + wcol * 64 + j * 16 + ln15;
                const float c = c_lds[m];
#pragma unroll
                for (int r = 0; r < 4; ++r) {
                    const float d = acc[i][j][r] - c;
                    p[i * 4 + r] += d * d;
                }
            }
    }

#pragma unroll
    for (int q = 0; q < 16; ++q) {
        float v = p[q];
        v += __shfl_xor(v, 1);
        v += __shfl_xor(v, 2);
        v += __shfl_xor(v, 4);
        v += __shfl_xor(v, 8);
        p[q] = v;
    }
    __syncthreads();
    if (ln15 == 0) {
#pragma unroll
        for (int i = 0; i < 4; ++i)
#pragma unroll
            for (int r = 0; r < 4; ++r)
                red[wcol][wrow * 64 + i * 16 + hi * 4 + r] = p[i * 4 + r];
    }
    __syncthreads();
    if (t < 128) {
        const float sq = (red[0][t] + red[1][t]) * (1.0f / 512.0f);
        const float lc = -50.0f * sq;
        const size_t b = (size_t)tile * 128 + t;
        out[b * NCLS + n] = expf(lc);
        out[(size_t)NBATCH * NCLS + b * NCLS + n] = lc;
    }
}

extern "C" void kernel_launch(void* const* d_in, const int* in_sizes, int n_in,
                              void* d_out, int out_size, void* d_ws, size_t ws_size,
                              hipStream_t stream) {
    const float* x    = (const float*)d_in[0];
    const float* w    = (const float*)d_in[1];
    const float* csum = (const float*)d_in[2];
    const float* cnum = (const float*)d_in[3];
    float* out = (float*)d_out;

    const size_t need = ((size_t)NBATCH * FDIM + (size_t)CDIM * NCLS * FDIM) * sizeof(unsigned short);

    if (ws_size >= need) {
        unsigned short* xb = (unsigned short*)d_ws;
        unsigned short* wb = xb + (size_t)NBATCH * FDIM;
        cvt_x_kernel<<<dim3((NBATCH * FDIM) / 2048), dim3(256), 0, stream>>>(x, xb);
        cvt_w_kernel<<<dim3(CDIM * NCLS), dim3(128), 0, stream>>>(w, wb);
        duq8<<<dim3(NCLS * 16), dim3(512), 0, stream>>>(xb, wb, csum, cnum, out);
    } else {
        duq_fallback<<<dim3(NCLS * 32), dim3(256), 0, stream>>>(x, w, csum, cnum, out);
    }
}